// Round 1
// baseline (114.575 us; speedup 1.0000x reference)
//
#include <hip/hip_runtime.h>
#include <hip/hip_bf16.h>

typedef __attribute__((ext_vector_type(4))) float f32x4;
typedef __attribute__((ext_vector_type(8))) short s16x8;
typedef __attribute__((ext_vector_type(4))) unsigned int u32x4;

// Problem constants: B*R*C = 3136 positions, n_caps=10, n_in=64, d_in=16, d_out=16.
// inputs: [3136][64][16] f32, W: [10][64][16][16] f32, out: [3136][10][16] f32.
//
// Gram-space routing: per (pos,n): R[i,o] (64x16); G = R^T R (16x16, MFMA);
// s0 = (1/64) R^T 1 (MFMA with ones-A); s_{t+1} = s_t + G squash(s_t); out=squash(s2).

__global__ __launch_bounds__(256) void caps_routing_kernel(
    const float* __restrict__ inp,
    const float* __restrict__ W,
    float* __restrict__ out)
{
    const int tid  = threadIdx.x;
    const int wid  = tid >> 6;
    const int lane = tid & 63;
    const int g    = blockIdx.x * 4 + wid;   // global wave id: 0..7839
    const int quad = g / 10;                 // position quad: 0..783
    const int n    = g - quad * 10;          // capsule n: 0..9
    const int pos0 = quad * 4;

    // per-wave bf16 res buffer: 64 rows x 16 cols (2 KB/wave)
    __shared__ __align__(16) unsigned short res_lds[4][64 * 16];
    unsigned short* myres = res_lds[wid];

    // ---------------- einsum: r[p][o] = sum_e inp[pos,i=lane,e] * W[n,i=lane,e,o]
    f32x4 r[4][4];
#pragma unroll
    for (int p = 0; p < 4; ++p)
#pragma unroll
        for (int q = 0; q < 4; ++q)
            r[p][q] = (f32x4)0.0f;

    const float* wbase = W + (size_t)((n * 64 + lane) * 16) * 16;
    const float* abase = inp + (size_t)pos0 * 1024 + lane * 16;

#pragma unroll
    for (int e = 0; e < 16; ++e) {
        f32x4 w0 = *(const f32x4*)(wbase + e * 16 + 0);
        f32x4 w1 = *(const f32x4*)(wbase + e * 16 + 4);
        f32x4 w2 = *(const f32x4*)(wbase + e * 16 + 8);
        f32x4 w3 = *(const f32x4*)(wbase + e * 16 + 12);
        float a0 = abase[0 * 1024 + e];
        float a1 = abase[1 * 1024 + e];
        float a2 = abase[2 * 1024 + e];
        float a3 = abase[3 * 1024 + e];
        r[0][0] += a0 * w0; r[0][1] += a0 * w1; r[0][2] += a0 * w2; r[0][3] += a0 * w3;
        r[1][0] += a1 * w0; r[1][1] += a1 * w1; r[1][2] += a1 * w2; r[1][3] += a1 * w3;
        r[2][0] += a2 * w0; r[2][1] += a2 * w1; r[2][2] += a2 * w2; r[2][3] += a2 * w3;
        r[3][0] += a3 * w0; r[3][1] += a3 * w1; r[3][2] += a3 * w2; r[3][3] += a3 * w3;
    }

    const int col = lane & 15;
    const int kg  = lane >> 4;

    s16x8 ones;
#pragma unroll
    for (int j = 0; j < 8; ++j) ones[j] = (short)0x3F80;  // bf16 1.0

#pragma unroll
    for (int p = 0; p < 4; ++p) {
        // ---- pack r[p] (fp32) to bf16 row, store row i=lane to LDS
        unsigned int u[8];
#pragma unroll
        for (int q = 0; q < 4; ++q) {
            __hip_bfloat16 b0 = __float2bfloat16(r[p][q][0]);
            __hip_bfloat16 b1 = __float2bfloat16(r[p][q][1]);
            __hip_bfloat16 b2 = __float2bfloat16(r[p][q][2]);
            __hip_bfloat16 b3 = __float2bfloat16(r[p][q][3]);
            unsigned short s0 = *(unsigned short*)&b0;
            unsigned short s1 = *(unsigned short*)&b1;
            unsigned short s2 = *(unsigned short*)&b2;
            unsigned short s3 = *(unsigned short*)&b3;
            u[q * 2 + 0] = (unsigned int)s0 | ((unsigned int)s1 << 16);
            u[q * 2 + 1] = (unsigned int)s2 | ((unsigned int)s3 << 16);
        }
        u32x4* dst = (u32x4*)myres + lane * 2;
        dst[0] = (u32x4){u[0], u[1], u[2], u[3]};
        dst[1] = (u32x4){u[4], u[5], u[6], u[7]};

        // ---- read MFMA fragments: lane l holds res[c*32 + kg*8 + j][col]
        // (A-frag of R^T and B-frag of R have identical register contents)
        s16x8 fr0, fr1;
#pragma unroll
        for (int j = 0; j < 8; ++j)
            fr0[j] = (short)myres[(0 * 32 + kg * 8 + j) * 16 + col];
#pragma unroll
        for (int j = 0; j < 8; ++j)
            fr1[j] = (short)myres[(1 * 32 + kg * 8 + j) * 16 + col];

        f32x4 G  = (f32x4)0.0f;
        f32x4 C2 = (f32x4)0.0f;
        G  = __builtin_amdgcn_mfma_f32_16x16x32_bf16(fr0, fr0, G, 0, 0, 0);
        G  = __builtin_amdgcn_mfma_f32_16x16x32_bf16(fr1, fr1, G, 0, 0, 0);
        C2 = __builtin_amdgcn_mfma_f32_16x16x32_bf16(ones, fr0, C2, 0, 0, 0);
        C2 = __builtin_amdgcn_mfma_f32_16x16x32_bf16(ones, fr1, C2, 0, 0, 0);
        // G frag: reg rr holds G[row = kg*4+rr][col];  C2: colsum (all rows equal)

        float s = C2[0] * (1.0f / 64.0f);   // s0[col]

#pragma unroll
        for (int t = 0; t < 2; ++t) {
            float sn = s * s;
            sn += __shfl_xor(sn, 1);
            sn += __shfl_xor(sn, 2);
            sn += __shfl_xor(sn, 4);
            sn += __shfl_xor(sn, 8);            // sn = sum_o s[o]^2
            float scale = sqrtf(sn) / (1.0f + sn);
            float v = scale * s;                // v[col] = squash(s)[col]
            // gather v[o'] for o' = kg*4 + rr (lanes 0..15 hold v[o=lane])
            float v0 = __shfl(v, kg * 4 + 0);
            float v1 = __shfl(v, kg * 4 + 1);
            float v2 = __shfl(v, kg * 4 + 2);
            float v3 = __shfl(v, kg * 4 + 3);
            // (G v)[col] via symmetry: sum over rows o' of column col
            float acc = G[0] * v0 + G[1] * v1 + G[2] * v2 + G[3] * v3;
            acc += __shfl_xor(acc, 16);
            acc += __shfl_xor(acc, 32);
            s += acc;
        }

        float sn = s * s;
        sn += __shfl_xor(sn, 1);
        sn += __shfl_xor(sn, 2);
        sn += __shfl_xor(sn, 4);
        sn += __shfl_xor(sn, 8);
        float scale = sqrtf(sn) / (1.0f + sn);
        float v = scale * s;

        if (lane < 16)
            out[(size_t)((pos0 + p) * 10 + n) * 16 + lane] = v;
    }
}

extern "C" void kernel_launch(void* const* d_in, const int* in_sizes, int n_in,
                              void* d_out, int out_size, void* d_ws, size_t ws_size,
                              hipStream_t stream) {
    const float* inp = (const float*)d_in[0];   // [3136][64][16]
    const float* W   = (const float*)d_in[1];   // [10][64][16][16]
    float* out = (float*)d_out;                 // [3136][10][16]

    // 3136 positions / 4 per wave * 10 n = 7840 waves = 1960 blocks of 4 waves
    dim3 grid(1960), block(256);
    hipLaunchKernelGGL(caps_routing_kernel, grid, block, 0, stream, inp, W, out);
}